// Round 6
// baseline (428.068 us; speedup 1.0000x reference)
//
#include <hip/hip_runtime.h>
#include <hip/hip_bf16.h>
#include <cstdint>
#include <cstddef>

#define B_ 4
#define S_ 2048
#define E_ 1024
#define H_ 16
#define D_ 64
#define NEG_BIG (-1e30f)
#define SC2 0.18033688011112043f   /* 0.125 * log2(e) */

typedef __bf16 bf16x8 __attribute__((ext_vector_type(8)));
typedef __bf16 bf16x4v __attribute__((ext_vector_type(4)));
typedef float f32x4 __attribute__((ext_vector_type(4)));

__device__ __forceinline__ void async_copy16(void* lds, const void* g) {
  __builtin_amdgcn_global_load_lds(
      (const __attribute__((address_space(1))) void*)g,
      (__attribute__((address_space(3))) void*)lds, 16, 0, 0);
}

__device__ __forceinline__ float bfu2f(unsigned short u) {
  unsigned v = ((unsigned)u) << 16;
  float f;
  __builtin_memcpy(&f, &v, 4);
  return f;
}
__device__ __forceinline__ unsigned short f2bfu(float f) {
  __hip_bfloat16 h = __float2bfloat16(f);  // RNE
  unsigned short u;
  __builtin_memcpy(&u, &h, 2);
  return u;
}
__device__ __forceinline__ unsigned pk2(float a, float b) {
  return (unsigned)f2bfu(a) | ((unsigned)f2bfu(b) << 16);
}

// ---------------- dtype probe (proven) ----------------
__global__ __launch_bounds__(256) void probe_dtype(
    const unsigned short* __restrict__ xr, int* __restrict__ flagp) {
  __shared__ int cnt;
  if (threadIdx.x == 0) cnt = 0;
  __syncthreads();
  int bad = 0;
  for (int i = 0; i < 32; ++i) {
    unsigned short u = xr[(threadIdx.x * 32 + i) * 2];
    int e = (u >> 7) & 0xFF;
    if (e == 0xFF || e >= 0x90 || (e != 0 && e <= 0x60)) bad++;
  }
  atomicAdd(&cnt, bad);
  __syncthreads();
  if (threadIdx.x == 0) *flagp = (cnt > 512) ? 0 : 1;  // 0=fp32, 1=bf16
}

__global__ __launch_bounds__(256) void convert_to_f32(
    const void* __restrict__ in, float* __restrict__ out,
    const int* __restrict__ flagp, int n) {
  int i = blockIdx.x * blockDim.x + threadIdx.x;
  if (i >= n) return;
  out[i] = (*flagp == 0) ? ((const float*)in)[i]
                         : bfu2f(((const unsigned short*)in)[i]);
}

// pad mask -> additive bias in score domain (0 or -1e30)
__global__ __launch_bounds__(256) void mask_bias(
    const int* __restrict__ am, float* __restrict__ mb, int n) {
  int i = blockIdx.x * blockDim.x + threadIdx.x;
  if (i < n) mb[i] = am[i] ? 0.f : NEG_BIG;
}

// transpose + convert: out_bf16[C][R] = in[R][C]   (proven)
__global__ __launch_bounds__(256) void transpose_conv(
    const void* __restrict__ in, unsigned short* __restrict__ out,
    const int* __restrict__ flagp, int R, int C) {
  __shared__ unsigned short t[32][33];
  const int flag = *flagp;
  const int c0 = blockIdx.x * 32, r0 = blockIdx.y * 32;
  const int lc = threadIdx.x & 31, lr = threadIdx.x >> 5;
  for (int i = 0; i < 4; ++i) {
    int r = lr + i * 8;
    size_t idx = (size_t)(r0 + r) * C + c0 + lc;
    t[r][lc] = (flag == 0) ? f2bfu(((const float*)in)[idx])
                           : ((const unsigned short*)in)[idx];
  }
  __syncthreads();
  for (int i = 0; i < 4; ++i) {
    int r = lr + i * 8;
    out[(size_t)(c0 + r) * R + r0 + lc] = t[lc][r];
  }
}

// -------- GEMM1: qkv = x(fp32|bf16) @ WqkvT^T + bias, out bf16 (proven) ----
__global__ __launch_bounds__(256) void gemm_x_w(
    const void* __restrict__ Xin, long long xoff,
    const __hip_bfloat16* __restrict__ Bt,
    const float* __restrict__ bias,
    const int* __restrict__ flagp,
    __hip_bfloat16* __restrict__ C,
    int M, int N, int K) {
  __shared__ __align__(16) __hip_bfloat16 As[128 * 32];
  __shared__ __align__(16) __hip_bfloat16 Bs[128 * 32];
  const int flag = *flagp;
  const int tid = threadIdx.x;
  const int m0 = blockIdx.x * 128, n0 = blockIdx.y * 128;
  const int w = tid >> 6, lane = tid & 63;
  const int wm = (w & 1) * 64, wn = (w >> 1) * 64;
  const int lm = lane & 15, kg = lane >> 4;
  const int e0 = tid * 8, e1 = tid * 8 + 2048;
  const int ra = e0 >> 5, ca = e0 & 31, rb = e1 >> 5, cb = e1 & 31;

  f32x4 acc[4][4] = {};

  for (int k0 = 0; k0 < K; k0 += 32) {
    uint4 aw0, aw1;
    if (flag == 0) {
      const float* A32 = (const float*)Xin + xoff;
      float4 f0 = *(const float4*)(A32 + (size_t)(m0 + ra) * K + k0 + ca);
      float4 f1 = *(const float4*)(A32 + (size_t)(m0 + ra) * K + k0 + ca + 4);
      float4 f2 = *(const float4*)(A32 + (size_t)(m0 + rb) * K + k0 + cb);
      float4 f3 = *(const float4*)(A32 + (size_t)(m0 + rb) * K + k0 + cb + 4);
      aw0 = make_uint4(pk2(f0.x, f0.y), pk2(f0.z, f0.w), pk2(f1.x, f1.y), pk2(f1.z, f1.w));
      aw1 = make_uint4(pk2(f2.x, f2.y), pk2(f2.z, f2.w), pk2(f3.x, f3.y), pk2(f3.z, f3.w));
    } else {
      const unsigned short* A16 = (const unsigned short*)Xin + xoff;
      aw0 = *(const uint4*)(A16 + (size_t)(m0 + ra) * K + k0 + ca);
      aw1 = *(const uint4*)(A16 + (size_t)(m0 + rb) * K + k0 + cb);
    }
    __syncthreads();
    *(uint4*)(As + e0) = aw0;
    *(uint4*)(As + e1) = aw1;
    for (int c = 0; c < 2; ++c) {
      int o = tid * 16 + c * 4096;
      int e = o >> 1, row = e >> 5, col = e & 31;
      async_copy16((char*)Bs + o, (const char*)(Bt + (size_t)(n0 + row) * K + k0 + col));
    }
    __syncthreads();
    bf16x8 af[4], bfrag[4];
    for (int t = 0; t < 4; ++t)
      af[t] = *(const bf16x8*)(As + (wm + t * 16 + lm) * 32 + kg * 8);
    for (int t = 0; t < 4; ++t)
      bfrag[t] = *(const bf16x8*)(Bs + (wn + t * 16 + lm) * 32 + kg * 8);
    for (int tm = 0; tm < 4; ++tm)
      for (int tn = 0; tn < 4; ++tn)
        acc[tm][tn] = __builtin_amdgcn_mfma_f32_16x16x32_bf16(af[tm], bfrag[tn], acc[tm][tn], 0, 0, 0);
  }

  for (int tn = 0; tn < 4; ++tn) {
    int col = n0 + wn + tn * 16 + lm;
    float bv = bias[col];
    for (int tm = 0; tm < 4; ++tm) {
      int rbase = m0 + wm + tm * 16 + kg * 4;
      for (int r = 0; r < 4; ++r)
        C[(size_t)(rbase + r) * N + col] = __float2bfloat16(acc[tm][tn][r] + bv);
    }
  }
}

// -------- GEMM2: out = attno @ WprojT^T + bias; out dtype by flag (proven) --
__global__ __launch_bounds__(256) void gemm_p_out(
    const __hip_bfloat16* __restrict__ A,
    const __hip_bfloat16* __restrict__ Bt,
    const float* __restrict__ bias,
    const int* __restrict__ flagp,
    void* __restrict__ Cv, long long coff,
    int M, int N, int K) {
  __shared__ __align__(16) __hip_bfloat16 As[128 * 32];
  __shared__ __align__(16) __hip_bfloat16 Bs[128 * 32];
  const int flag = *flagp;
  const int tid = threadIdx.x;
  const int m0 = blockIdx.x * 128, n0 = blockIdx.y * 128;
  const int w = tid >> 6, lane = tid & 63;
  const int wm = (w & 1) * 64, wn = (w >> 1) * 64;
  const int lm = lane & 15, kg = lane >> 4;

  f32x4 acc[4][4] = {};

  for (int k0 = 0; k0 < K; k0 += 32) {
    __syncthreads();
    for (int c = 0; c < 2; ++c) {
      int o = tid * 16 + c * 4096;
      int e = o >> 1, row = e >> 5, col = e & 31;
      async_copy16((char*)As + o, (const char*)(A + (size_t)(m0 + row) * K + k0 + col));
      async_copy16((char*)Bs + o, (const char*)(Bt + (size_t)(n0 + row) * K + k0 + col));
    }
    __syncthreads();
    bf16x8 af[4], bfrag[4];
    for (int t = 0; t < 4; ++t)
      af[t] = *(const bf16x8*)(As + (wm + t * 16 + lm) * 32 + kg * 8);
    for (int t = 0; t < 4; ++t)
      bfrag[t] = *(const bf16x8*)(Bs + (wn + t * 16 + lm) * 32 + kg * 8);
    for (int tm = 0; tm < 4; ++tm)
      for (int tn = 0; tn < 4; ++tn)
        acc[tm][tn] = __builtin_amdgcn_mfma_f32_16x16x32_bf16(af[tm], bfrag[tn], acc[tm][tn], 0, 0, 0);
  }

  for (int tn = 0; tn < 4; ++tn) {
    int col = n0 + wn + tn * 16 + lm;
    float bv = bias[col];
    for (int tm = 0; tm < 4; ++tm) {
      int rbase = m0 + wm + tm * 16 + kg * 4;
      for (int r = 0; r < 4; ++r) {
        float v = acc[tm][tn][r] + bv;
        size_t idx = (size_t)coff + (size_t)(rbase + r) * N + col;
        if (flag == 0) ((float*)Cv)[idx] = v;
        else           ((unsigned short*)Cv)[idx] = f2bfu(v);
      }
    }
  }
}

// -------- causal flash attention v2 --------
// 512 threads (8 waves), 128 q-rows/block, 64-key tiles, double-buffered K/V,
// ONE barrier per tile; softmax in exp2 domain; wave-private Ps (stride 72).
// grid: (S/128 = 16, bsz*H); qt reversed so heavy blocks dispatch first.
#define VSTR 72
__global__ __launch_bounds__(512, 4) void attn_flash(
    const __hip_bfloat16* __restrict__ qkv,  // [bsz*S][3072]
    const float* __restrict__ mbias,         // [bsz*S] 0 / -1e30
    __hip_bfloat16* __restrict__ outp) {     // [bsz*S][1024]
  __shared__ __align__(16) __hip_bfloat16 Ks[2][64 * 64];
  __shared__ __align__(16) __hip_bfloat16 VT[2][64 * VSTR];
  __shared__ __align__(16) __hip_bfloat16 Ps[8][16 * VSTR];

  const int tid = threadIdx.x;
  const int qt = (gridDim.x - 1) - blockIdx.x;   // LPT: heavy first
  const int bh = blockIdx.y;
  const int b = bh >> 4, h = bh & 15;
  const int q0 = qt * 128;
  const size_t rowbase = (size_t)b * S_;
  const int w = tid >> 6, lane = tid & 63;
  const int lm = lane & 15, kg = lane >> 4;
  const int qg = q0 + w * 16 + lm;
  __hip_bfloat16* PsW = Ps[w];

  // Q fragments (B-operand of S^T = K·Q^T), persistent
  bf16x8 bq0 = *(const bf16x8*)(qkv + (rowbase + qg) * 3072 + h * 64 + kg * 8);
  bf16x8 bq1 = *(const bf16x8*)(qkv + (rowbase + qg) * 3072 + h * 64 + 32 + kg * 8);

  const int jmax = 2 * qt + 1;

  {  // prologue: stage tile 0 into buffer 0
    const char* kb = (const char*)(qkv + rowbase * 3072 + 1024 + h * 64);
    const int o = tid * 16;
    async_copy16((char*)Ks[0] + o, kb + (size_t)(o >> 7) * 6144 + (o & 127));
    uint4 vv = *(const uint4*)(qkv + (rowbase + lane) * 3072 + 2048 + h * 64 + w * 8);
    const __hip_bfloat16* pv = (const __hip_bfloat16*)&vv;
    #pragma unroll
    for (int e = 0; e < 8; ++e) VT[0][(w * 8 + e) * VSTR + lane] = pv[e];
  }
  float4 mb[4];
  #pragma unroll
  for (int ct = 0; ct < 4; ++ct)
    mb[ct] = *(const float4*)(mbias + rowbase + ct * 16 + kg * 4);

  float mrow = NEG_BIG, lrow = 0.f;
  f32x4 oacc[4] = {};
  int buf = 0;

  for (int j = 0; j <= jmax; ++j) {
    __syncthreads();  // staging of buf landed (vmcnt+lgkm); nbuf readers done
    const int nbuf = buf ^ 1;
    const bool pre = (j < jmax);
    uint4 vv_next;
    float4 mbn[4];
    if (pre) {  // prefetch tile j+1 into nbuf (overlaps this tile's compute)
      const int jn0 = (j + 1) * 64;
      const char* kb = (const char*)(qkv + (rowbase + jn0) * 3072 + 1024 + h * 64);
      const int o = tid * 16;
      async_copy16((char*)Ks[nbuf] + o, kb + (size_t)(o >> 7) * 6144 + (o & 127));
      vv_next = *(const uint4*)(qkv + (rowbase + jn0 + lane) * 3072 + 2048 + h * 64 + w * 8);
      #pragma unroll
      for (int ct = 0; ct < 4; ++ct)
        mbn[ct] = *(const float4*)(mbias + rowbase + jn0 + ct * 16 + kg * 4);
    }
    const int j0 = j * 64;

    // S^T = K · Q^T   (A=Ks[key][d], B=Q[q][d]); D: row=key, col=q
    f32x4 sacc[4] = {};
    #pragma unroll
    for (int ks = 0; ks < 2; ++ks) {
      bf16x8 bq = ks ? bq1 : bq0;
      #pragma unroll
      for (int ct = 0; ct < 4; ++ct) {
        bf16x8 ak = *(const bf16x8*)(Ks[buf] + (ct * 16 + lm) * 64 + ks * 32 + kg * 8);
        sacc[ct] = __builtin_amdgcn_mfma_f32_16x16x32_bf16(ak, bq, sacc[ct], 0, 0, 0);
      }
    }
    // softmax (log2 domain): t = s*0.125*log2e + padbias
    float t[4][4];
    float mt = NEG_BIG;
    if (j >= 2 * qt) {  // diagonal tiles: per-element causal (block-uniform branch)
      #pragma unroll
      for (int ct = 0; ct < 4; ++ct) {
        const float* mp = (const float*)&mb[ct];
        #pragma unroll
        for (int r = 0; r < 4; ++r) {
          int keyg = j0 + ct * 16 + kg * 4 + r;
          float v = fmaf(sacc[ct][r], SC2, mp[r]);
          v = (keyg <= qg) ? v : NEG_BIG;
          t[ct][r] = v;
          mt = fmaxf(mt, v);
        }
      }
    } else {            // interior tiles: no causal check
      #pragma unroll
      for (int ct = 0; ct < 4; ++ct) {
        const float* mp = (const float*)&mb[ct];
        #pragma unroll
        for (int r = 0; r < 4; ++r) {
          float v = fmaf(sacc[ct][r], SC2, mp[r]);
          t[ct][r] = v;
          mt = fmaxf(mt, v);
        }
      }
    }
    mt = fmaxf(mt, __shfl_xor(mt, 16));
    mt = fmaxf(mt, __shfl_xor(mt, 32));
    const float mn = fmaxf(mrow, mt);
    const float a = __builtin_exp2f(mrow - mn);  // first iter: 0
    float ps = 0.f;
    #pragma unroll
    for (int ct = 0; ct < 4; ++ct) {
      float p0 = __builtin_exp2f(t[ct][0] - mn), p1 = __builtin_exp2f(t[ct][1] - mn);
      float p2 = __builtin_exp2f(t[ct][2] - mn), p3 = __builtin_exp2f(t[ct][3] - mn);
      ps += (p0 + p1) + (p2 + p3);
      bf16x4v pv;
      pv[0] = (__bf16)p0; pv[1] = (__bf16)p1; pv[2] = (__bf16)p2; pv[3] = (__bf16)p3;
      *(bf16x4v*)(PsW + lm * VSTR + ct * 16 + kg * 4) = pv;  // wave-private
    }
    ps += __shfl_xor(ps, 16);
    ps += __shfl_xor(ps, 32);
    lrow = lrow * a + ps;
    mrow = mn;
    float al[4];
    #pragma unroll
    for (int r = 0; r < 4; ++r) al[r] = __shfl(a, kg * 4 + r);
    #pragma unroll
    for (int ct2 = 0; ct2 < 4; ++ct2) {
      oacc[ct2][0] *= al[0]; oacc[ct2][1] *= al[1];
      oacc[ct2][2] *= al[2]; oacc[ct2][3] *= al[3];
    }
    // O += P·V (A = Ps wave-private — same-wave DS in-order, no barrier)
    #pragma unroll
    for (int ks = 0; ks < 2; ++ks) {
      bf16x8 ap = *(const bf16x8*)(PsW + lm * VSTR + ks * 32 + kg * 8);
      #pragma unroll
      for (int ct2 = 0; ct2 < 4; ++ct2) {
        bf16x8 bv = *(const bf16x8*)(VT[buf] + (ct2 * 16 + lm) * VSTR + ks * 32 + kg * 8);
        oacc[ct2] = __builtin_amdgcn_mfma_f32_16x16x32_bf16(ap, bv, oacc[ct2], 0, 0, 0);
      }
    }
    if (pre) {  // finish staging of nbuf (VT) — races impossible post-barrier
      const __hip_bfloat16* pv = (const __hip_bfloat16*)&vv_next;
      #pragma unroll
      for (int e = 0; e < 8; ++e) VT[nbuf][(w * 8 + e) * VSTR + lane] = pv[e];
      #pragma unroll
      for (int ct = 0; ct < 4; ++ct) mb[ct] = mbn[ct];
    }
    buf = nbuf;
  }

  {  // epilogue: O / l
    float linv = (lrow > 0.f) ? 1.f / lrow : 0.f;
    float li[4];
    #pragma unroll
    for (int r = 0; r < 4; ++r) li[r] = __shfl(linv, kg * 4 + r);
    #pragma unroll
    for (int ct2 = 0; ct2 < 4; ++ct2) {
      #pragma unroll
      for (int r = 0; r < 4; ++r) {
        int rowq = q0 + w * 16 + kg * 4 + r;
        outp[(rowbase + rowq) * 1024 + h * 64 + ct2 * 16 + lm] =
            __float2bfloat16(oacc[ct2][r] * li[r]);
      }
    }
  }
}

extern "C" void kernel_launch(void* const* d_in, const int* in_sizes, int n_in,
                              void* d_out, int out_size, void* d_ws, size_t ws_size,
                              hipStream_t stream) {
  // ws: [0] flag | [1K] bq | [16K] bp | [32K] maskbias 32KB | [64K] WqkvT 6MB |
  // [64K+6MB] WprojT 2MB | big = 64K+8MB: qkv (+ attno).
  const bool merged = (ws_size >= (80ull << 20));
  char* ws = (char*)d_ws;
  int*            flag   = (int*)ws;
  float*          bq     = (float*)(ws + 1024);
  float*          bp     = (float*)(ws + 16384);
  float*          mbias  = (float*)(ws + 32768);
  unsigned short* WqkvTu = (unsigned short*)(ws + 65536);
  unsigned short* WprojTu= (unsigned short*)(ws + 65536 + 6291456);
  char*           big    = ws + 65536 + 8388608;
  __hip_bfloat16* qkv    = (__hip_bfloat16*)big;
  __hip_bfloat16* attno  = (__hip_bfloat16*)(big + (merged ? 50331648u : 12582912u));

  probe_dtype<<<1, 256, 0, stream>>>((const unsigned short*)d_in[0], flag);
  convert_to_f32<<<12, 256, 0, stream>>>(d_in[3], bq, flag, 3072);
  convert_to_f32<<<4, 256, 0, stream>>>(d_in[5], bp, flag, 1024);
  mask_bias<<<(B_ * S_) / 256, 256, 0, stream>>>((const int*)d_in[1], mbias, B_ * S_);
  transpose_conv<<<dim3(96, 32), 256, 0, stream>>>(d_in[2], WqkvTu, flag, 1024, 3072);
  transpose_conv<<<dim3(32, 32), 256, 0, stream>>>(d_in[4], WprojTu, flag, 1024, 1024);

  const int nchunk = merged ? 1 : B_;
  const int bsz = merged ? B_ : 1;
  const int Mc = bsz * S_;
  for (int c = 0; c < nchunk; ++c) {
    long long off = (long long)c * S_ * E_;
    gemm_x_w<<<dim3(Mc / 128, 3072 / 128), 256, 0, stream>>>(
        d_in[0], off, (const __hip_bfloat16*)WqkvTu, bq, flag, qkv, Mc, 3072, 1024);
    attn_flash<<<dim3(S_ / 128, bsz * H_), 512, 0, stream>>>(
        qkv, mbias + (size_t)c * S_, attno);
    gemm_p_out<<<dim3(Mc / 128, 1024 / 128), 256, 0, stream>>>(
        attno, (const __hip_bfloat16*)WprojTu, bp, flag, d_out, off, Mc, 1024, 1024);
  }
}

// Round 7
// 384.620 us; speedup vs baseline: 1.1130x; 1.1130x over previous
//
#include <hip/hip_runtime.h>
#include <hip/hip_bf16.h>
#include <cstdint>
#include <cstddef>

#define B_ 4
#define S_ 2048
#define E_ 1024
#define H_ 16
#define D_ 64
#define NEG_BIG (-1e30f)
#define SC2 0.18033688011112043f   /* 0.125 * log2(e) */

typedef __bf16 bf16x8 __attribute__((ext_vector_type(8)));
typedef __bf16 bf16x4v __attribute__((ext_vector_type(4)));
typedef float f32x4 __attribute__((ext_vector_type(4)));

__device__ __forceinline__ void async_copy16(void* lds, const void* g) {
  __builtin_amdgcn_global_load_lds(
      (const __attribute__((address_space(1))) void*)g,
      (__attribute__((address_space(3))) void*)lds, 16, 0, 0);
}

__device__ __forceinline__ float bfu2f(unsigned short u) {
  unsigned v = ((unsigned)u) << 16;
  float f;
  __builtin_memcpy(&f, &v, 4);
  return f;
}
__device__ __forceinline__ unsigned short f2bfu(float f) {
  __hip_bfloat16 h = __float2bfloat16(f);  // RNE
  unsigned short u;
  __builtin_memcpy(&u, &h, 2);
  return u;
}
__device__ __forceinline__ unsigned pk2(float a, float b) {
  return (unsigned)f2bfu(a) | ((unsigned)f2bfu(b) << 16);
}

// ---------------- dtype probe (proven) ----------------
__global__ __launch_bounds__(256) void probe_dtype(
    const unsigned short* __restrict__ xr, int* __restrict__ flagp) {
  __shared__ int cnt;
  if (threadIdx.x == 0) cnt = 0;
  __syncthreads();
  int bad = 0;
  for (int i = 0; i < 32; ++i) {
    unsigned short u = xr[(threadIdx.x * 32 + i) * 2];
    int e = (u >> 7) & 0xFF;
    if (e == 0xFF || e >= 0x90 || (e != 0 && e <= 0x60)) bad++;
  }
  atomicAdd(&cnt, bad);
  __syncthreads();
  if (threadIdx.x == 0) *flagp = (cnt > 512) ? 0 : 1;  // 0=fp32, 1=bf16
}

__global__ __launch_bounds__(256) void convert_to_f32(
    const void* __restrict__ in, float* __restrict__ out,
    const int* __restrict__ flagp, int n) {
  int i = blockIdx.x * blockDim.x + threadIdx.x;
  if (i >= n) return;
  out[i] = (*flagp == 0) ? ((const float*)in)[i]
                         : bfu2f(((const unsigned short*)in)[i]);
}

// pad mask -> additive bias (0 / -1e30)
__global__ __launch_bounds__(256) void mask_bias(
    const int* __restrict__ am, float* __restrict__ mb, int n) {
  int i = blockIdx.x * blockDim.x + threadIdx.x;
  if (i < n) mb[i] = am[i] ? 0.f : NEG_BIG;
}

// transpose + convert: out_bf16[C][R] = in[R][C]   (proven)
__global__ __launch_bounds__(256) void transpose_conv(
    const void* __restrict__ in, unsigned short* __restrict__ out,
    const int* __restrict__ flagp, int R, int C) {
  __shared__ unsigned short t[32][33];
  const int flag = *flagp;
  const int c0 = blockIdx.x * 32, r0 = blockIdx.y * 32;
  const int lc = threadIdx.x & 31, lr = threadIdx.x >> 5;
  for (int i = 0; i < 4; ++i) {
    int r = lr + i * 8;
    size_t idx = (size_t)(r0 + r) * C + c0 + lc;
    t[r][lc] = (flag == 0) ? f2bfu(((const float*)in)[idx])
                           : ((const unsigned short*)in)[idx];
  }
  __syncthreads();
  for (int i = 0; i < 4; ++i) {
    int r = lr + i * 8;
    out[(size_t)(c0 + r) * R + r0 + lc] = t[lc][r];
  }
}

// -------- GEMM1: qkv = x(fp32|bf16) @ WqkvT^T + bias, out bf16 --------
// XOR-swizzled LDS tiles: chunk_in_lds ch' holds global chunk ch' ^ ((row>>1)&3)
// (64B rows -> 8-way conflicts become 2-way = free).
__global__ __launch_bounds__(256) void gemm_x_w(
    const void* __restrict__ Xin, long long xoff,
    const __hip_bfloat16* __restrict__ Bt,
    const float* __restrict__ bias,
    const int* __restrict__ flagp,
    __hip_bfloat16* __restrict__ C,
    int M, int N, int K) {
  __shared__ __align__(16) __hip_bfloat16 As[128 * 32];
  __shared__ __align__(16) __hip_bfloat16 Bs[128 * 32];
  const int flag = *flagp;
  const int tid = threadIdx.x;
  const int m0 = blockIdx.x * 128, n0 = blockIdx.y * 128;
  const int w = tid >> 6, lane = tid & 63;
  const int wm = (w & 1) * 64, wn = (w >> 1) * 64;
  const int lm = lane & 15, kg = lane >> 4;
  // A staging: lane writes 16B chunks at rows ra/ra+64, LDS chunk tid&3,
  // sourced from swizzled global column.
  const int e0 = tid * 8, e1 = tid * 8 + 2048;
  const int ra = tid >> 2;                       // rows 0..63 (and +64)
  const int sw = ((tid >> 3) & 3);               // (row>>1)&3, same for both halves
  const int ca = ((tid & 3) ^ sw) * 8;           // swizzled source column (elements)

  f32x4 acc[4][4] = {};

  for (int k0 = 0; k0 < K; k0 += 32) {
    uint4 aw0, aw1;
    if (flag == 0) {
      const float* A32 = (const float*)Xin + xoff;
      float4 f0 = *(const float4*)(A32 + (size_t)(m0 + ra) * K + k0 + ca);
      float4 f1 = *(const float4*)(A32 + (size_t)(m0 + ra) * K + k0 + ca + 4);
      float4 f2 = *(const float4*)(A32 + (size_t)(m0 + ra + 64) * K + k0 + ca);
      float4 f3 = *(const float4*)(A32 + (size_t)(m0 + ra + 64) * K + k0 + ca + 4);
      aw0 = make_uint4(pk2(f0.x, f0.y), pk2(f0.z, f0.w), pk2(f1.x, f1.y), pk2(f1.z, f1.w));
      aw1 = make_uint4(pk2(f2.x, f2.y), pk2(f2.z, f2.w), pk2(f3.x, f3.y), pk2(f3.z, f3.w));
    } else {
      const unsigned short* A16 = (const unsigned short*)Xin + xoff;
      aw0 = *(const uint4*)(A16 + (size_t)(m0 + ra) * K + k0 + ca);
      aw1 = *(const uint4*)(A16 + (size_t)(m0 + ra + 64) * K + k0 + ca);
    }
    __syncthreads();
    *(uint4*)(As + e0) = aw0;
    *(uint4*)(As + e1) = aw1;
    for (int c = 0; c < 2; ++c) {  // B via async DMA, swizzled source
      int o = tid * 16 + c * 4096;
      int row = o >> 6, chp = (o >> 4) & 3;
      int gch = chp ^ ((row >> 1) & 3);
      async_copy16((char*)Bs + o, (const char*)(Bt + (size_t)(n0 + row) * K + k0 + gch * 8));
    }
    __syncthreads();
    bf16x8 af[4], bfrag[4];
    for (int t = 0; t < 4; ++t) {
      int rt = wm + t * 16 + lm;
      int ch = kg ^ ((rt >> 1) & 3);
      af[t] = *(const bf16x8*)(As + rt * 32 + ch * 8);
    }
    for (int t = 0; t < 4; ++t) {
      int rt = wn + t * 16 + lm;
      int ch = kg ^ ((rt >> 1) & 3);
      bfrag[t] = *(const bf16x8*)(Bs + rt * 32 + ch * 8);
    }
    for (int tm = 0; tm < 4; ++tm)
      for (int tn = 0; tn < 4; ++tn)
        acc[tm][tn] = __builtin_amdgcn_mfma_f32_16x16x32_bf16(af[tm], bfrag[tn], acc[tm][tn], 0, 0, 0);
  }

  for (int tn = 0; tn < 4; ++tn) {
    int col = n0 + wn + tn * 16 + lm;
    float bv = bias[col];
    for (int tm = 0; tm < 4; ++tm) {
      int rbase = m0 + wm + tm * 16 + kg * 4;
      for (int r = 0; r < 4; ++r)
        C[(size_t)(rbase + r) * N + col] = __float2bfloat16(acc[tm][tn][r] + bv);
    }
  }
}

// -------- GEMM2: out = attno @ WprojT^T + bias; out dtype by flag --------
__global__ __launch_bounds__(256) void gemm_p_out(
    const __hip_bfloat16* __restrict__ A,
    const __hip_bfloat16* __restrict__ Bt,
    const float* __restrict__ bias,
    const int* __restrict__ flagp,
    void* __restrict__ Cv, long long coff,
    int M, int N, int K) {
  __shared__ __align__(16) __hip_bfloat16 As[128 * 32];
  __shared__ __align__(16) __hip_bfloat16 Bs[128 * 32];
  const int flag = *flagp;
  const int tid = threadIdx.x;
  const int m0 = blockIdx.x * 128, n0 = blockIdx.y * 128;
  const int w = tid >> 6, lane = tid & 63;
  const int wm = (w & 1) * 64, wn = (w >> 1) * 64;
  const int lm = lane & 15, kg = lane >> 4;

  f32x4 acc[4][4] = {};

  for (int k0 = 0; k0 < K; k0 += 32) {
    __syncthreads();
    for (int c = 0; c < 2; ++c) {
      int o = tid * 16 + c * 4096;
      int row = o >> 6, chp = (o >> 4) & 3;
      int gch = chp ^ ((row >> 1) & 3);
      async_copy16((char*)As + o, (const char*)(A + (size_t)(m0 + row) * K + k0 + gch * 8));
      async_copy16((char*)Bs + o, (const char*)(Bt + (size_t)(n0 + row) * K + k0 + gch * 8));
    }
    __syncthreads();
    bf16x8 af[4], bfrag[4];
    for (int t = 0; t < 4; ++t) {
      int rt = wm + t * 16 + lm;
      int ch = kg ^ ((rt >> 1) & 3);
      af[t] = *(const bf16x8*)(As + rt * 32 + ch * 8);
    }
    for (int t = 0; t < 4; ++t) {
      int rt = wn + t * 16 + lm;
      int ch = kg ^ ((rt >> 1) & 3);
      bfrag[t] = *(const bf16x8*)(Bs + rt * 32 + ch * 8);
    }
    for (int tm = 0; tm < 4; ++tm)
      for (int tn = 0; tn < 4; ++tn)
        acc[tm][tn] = __builtin_amdgcn_mfma_f32_16x16x32_bf16(af[tm], bfrag[tn], acc[tm][tn], 0, 0, 0);
  }

  for (int tn = 0; tn < 4; ++tn) {
    int col = n0 + wn + tn * 16 + lm;
    float bv = bias[col];
    for (int tm = 0; tm < 4; ++tm) {
      int rbase = m0 + wm + tm * 16 + kg * 4;
      for (int r = 0; r < 4; ++r) {
        float v = acc[tm][tn][r] + bv;
        size_t idx = (size_t)coff + (size_t)(rbase + r) * N + col;
        if (flag == 0) ((float*)Cv)[idx] = v;
        else           ((unsigned short*)Cv)[idx] = f2bfu(v);
      }
    }
  }
}

// -------- causal flash attention v3 --------
// 512 threads (8 waves), 128 q/block, 64-key tiles, double-buffered K/V,
// one barrier/tile. Ks XOR-swizzled (16-way -> 2-way conflicts).
// PV computed as O^T = V^T·P (D col = q = lane&15): alpha/linv rescale are
// per-lane scalars (no broadcast shuffles); l-sum deferred to epilogue.
#define VSTR 72
__global__ __launch_bounds__(512, 4) void attn_flash(
    const __hip_bfloat16* __restrict__ qkv,  // [bsz*S][3072]
    const float* __restrict__ mbias,         // [bsz*S] 0 / -1e30
    __hip_bfloat16* __restrict__ outp) {     // [bsz*S][1024]
  __shared__ __align__(16) __hip_bfloat16 Ks[2][64 * 64];   // [key][d], swizzled
  __shared__ __align__(16) __hip_bfloat16 VT[2][64 * VSTR]; // [d][key]
  __shared__ __align__(16) __hip_bfloat16 Ps[8][16 * VSTR]; // wave-private P[q][key]

  const int tid = threadIdx.x;
  const int qt = (gridDim.x - 1) - blockIdx.x;   // LPT: heavy first
  const int bh = blockIdx.y;
  const int b = bh >> 4, h = bh & 15;
  const int q0 = qt * 128;
  const size_t rowbase = (size_t)b * S_;
  const int w = tid >> 6, lane = tid & 63;
  const int lm = lane & 15, kg = lane >> 4;
  const int qg = q0 + w * 16 + lm;
  __hip_bfloat16* PsW = Ps[w];
  // K staging geometry (swizzled source)
  const int krow = tid >> 3;
  const int kgch = (tid & 7) ^ (krow & 7);

  // Q fragments (B-operand of S^T = K·Q^T), persistent
  bf16x8 bq0 = *(const bf16x8*)(qkv + (rowbase + qg) * 3072 + h * 64 + kg * 8);
  bf16x8 bq1 = *(const bf16x8*)(qkv + (rowbase + qg) * 3072 + h * 64 + 32 + kg * 8);

  const int jmax = 2 * qt + 1;

  {  // prologue: stage tile 0 into buffer 0
    const char* kb = (const char*)(qkv + rowbase * 3072 + 1024 + h * 64);
    async_copy16((char*)Ks[0] + tid * 16, kb + (size_t)krow * 6144 + kgch * 16);
    uint4 vv = *(const uint4*)(qkv + (rowbase + lane) * 3072 + 2048 + h * 64 + w * 8);
    const __hip_bfloat16* pv = (const __hip_bfloat16*)&vv;
    #pragma unroll
    for (int e = 0; e < 8; ++e) VT[0][(w * 8 + e) * VSTR + lane] = pv[e];
  }

  float mrow = NEG_BIG, plocal = 0.f;
  f32x4 oacc[4] = {};   // O^T[d][q]: col q=lm, row d = ct2*16 + kg*4 + r
  int buf = 0;

  for (int j = 0; j <= jmax; ++j) {
    __syncthreads();  // staging of buf landed (vmcnt+lgkm drain); nbuf readers done
    const int nbuf = buf ^ 1;
    const bool pre = (j < jmax);
    const int j0 = j * 64;
    uint4 vv_next;
    if (pre) {  // prefetch tile j+1 into nbuf
      const int jn0 = j0 + 64;
      const char* kb = (const char*)(qkv + (rowbase + jn0) * 3072 + 1024 + h * 64);
      async_copy16((char*)Ks[nbuf] + tid * 16, kb + (size_t)krow * 6144 + kgch * 16);
      vv_next = *(const uint4*)(qkv + (rowbase + jn0 + lane) * 3072 + 2048 + h * 64 + w * 8);
    }
    float4 mb[4];
    #pragma unroll
    for (int ct = 0; ct < 4; ++ct)
      mb[ct] = *(const float4*)(mbias + rowbase + j0 + ct * 16 + kg * 4);

    // S^T = K · Q^T   (A=Ks[key][d] swizzled, B=Q[q][d]); D: row=key, col=q
    f32x4 sacc[4] = {};
    #pragma unroll
    for (int ks = 0; ks < 2; ++ks) {
      bf16x8 bq = ks ? bq1 : bq0;
      #pragma unroll
      for (int ct = 0; ct < 4; ++ct) {
        int row = ct * 16 + lm;
        int ch = (ks * 4 + kg) ^ (row & 7);
        bf16x8 ak = *(const bf16x8*)(Ks[buf] + row * 64 + ch * 8);
        sacc[ct] = __builtin_amdgcn_mfma_f32_16x16x32_bf16(ak, bq, sacc[ct], 0, 0, 0);
      }
    }
    // softmax (log2 domain), in place
    float mt = NEG_BIG;
    if (j >= 2 * qt) {  // diagonal tiles: per-element causal
      #pragma unroll
      for (int ct = 0; ct < 4; ++ct) {
        const float* mp = (const float*)&mb[ct];
        #pragma unroll
        for (int r = 0; r < 4; ++r) {
          int keyg = j0 + ct * 16 + kg * 4 + r;
          float v = fmaf(sacc[ct][r], SC2, mp[r]);
          v = (keyg <= qg) ? v : NEG_BIG;
          sacc[ct][r] = v;
          mt = fmaxf(mt, v);
        }
      }
    } else {
      #pragma unroll
      for (int ct = 0; ct < 4; ++ct) {
        const float* mp = (const float*)&mb[ct];
        #pragma unroll
        for (int r = 0; r < 4; ++r) {
          float v = fmaf(sacc[ct][r], SC2, mp[r]);
          sacc[ct][r] = v;
          mt = fmaxf(mt, v);
        }
      }
    }
    mt = fmaxf(mt, __shfl_xor(mt, 16));
    mt = fmaxf(mt, __shfl_xor(mt, 32));
    const float mn = fmaxf(mrow, mt);
    const float a = __builtin_exp2f(mrow - mn);  // first iter: 0
    float psl = 0.f;
    #pragma unroll
    for (int ct = 0; ct < 4; ++ct) {
      float p0 = __builtin_exp2f(sacc[ct][0] - mn), p1 = __builtin_exp2f(sacc[ct][1] - mn);
      float p2 = __builtin_exp2f(sacc[ct][2] - mn), p3 = __builtin_exp2f(sacc[ct][3] - mn);
      psl += (p0 + p1) + (p2 + p3);
      bf16x4v pv;
      pv[0] = (__bf16)p0; pv[1] = (__bf16)p1; pv[2] = (__bf16)p2; pv[3] = (__bf16)p3;
      *(bf16x4v*)(PsW + lm * VSTR + ct * 16 + kg * 4) = pv;  // P[q=lm][keys]
    }
    plocal = plocal * a + psl;   // per-lane partial of l (exact recurrence)
    mrow = mn;
    #pragma unroll
    for (int ct2 = 0; ct2 < 4; ++ct2) {  // per-lane rescale (col q = lm)
      oacc[ct2][0] *= a; oacc[ct2][1] *= a;
      oacc[ct2][2] *= a; oacc[ct2][3] *= a;
    }
    // O^T += V^T · P   (A=VT[d][key], B=Ps[q][key]; same-wave DS in-order)
    #pragma unroll
    for (int ks = 0; ks < 2; ++ks) {
      bf16x8 bp = *(const bf16x8*)(PsW + lm * VSTR + ks * 32 + kg * 8);
      #pragma unroll
      for (int ct2 = 0; ct2 < 4; ++ct2) {
        bf16x8 av = *(const bf16x8*)(VT[buf] + (ct2 * 16 + lm) * VSTR + ks * 32 + kg * 8);
        oacc[ct2] = __builtin_amdgcn_mfma_f32_16x16x32_bf16(av, bp, oacc[ct2], 0, 0, 0);
      }
    }
    if (pre) {  // finish staging of nbuf (VT)
      const __hip_bfloat16* pv = (const __hip_bfloat16*)&vv_next;
      #pragma unroll
      for (int e = 0; e < 8; ++e) VT[nbuf][(w * 8 + e) * VSTR + lane] = pv[e];
    }
    buf = nbuf;
  }

  {  // epilogue: reduce l across kg, divide, pack 8B stores
    float l = plocal;
    l += __shfl_xor(l, 16);
    l += __shfl_xor(l, 32);
    float linv = (l > 0.f) ? 1.f / l : 0.f;
    __hip_bfloat16* ob = outp + (rowbase + q0 + w * 16 + lm) * 1024 + h * 64;
    #pragma unroll
    for (int ct2 = 0; ct2 < 4; ++ct2) {
      bf16x4v ov;
      ov[0] = (__bf16)(oacc[ct2][0] * linv);
      ov[1] = (__bf16)(oacc[ct2][1] * linv);
      ov[2] = (__bf16)(oacc[ct2][2] * linv);
      ov[3] = (__bf16)(oacc[ct2][3] * linv);
      *(bf16x4v*)(ob + ct2 * 16 + kg * 4) = ov;
    }
  }
}

extern "C" void kernel_launch(void* const* d_in, const int* in_sizes, int n_in,
                              void* d_out, int out_size, void* d_ws, size_t ws_size,
                              hipStream_t stream) {
  const bool merged = (ws_size >= (80ull << 20));
  char* ws = (char*)d_ws;
  int*            flag   = (int*)ws;
  float*          bq     = (float*)(ws + 1024);
  float*          bp     = (float*)(ws + 16384);
  float*          mbias  = (float*)(ws + 32768);
  unsigned short* WqkvTu = (unsigned short*)(ws + 65536);
  unsigned short* WprojTu= (unsigned short*)(ws + 65536 + 6291456);
  char*           big    = ws + 65536 + 8388608;
  __hip_bfloat16* qkv    = (__hip_bfloat16*)big;
  __hip_bfloat16* attno  = (__hip_bfloat16*)(big + (merged ? 50331648u : 12582912u));

  probe_dtype<<<1, 256, 0, stream>>>((const unsigned short*)d_in[0], flag);
  convert_to_f32<<<12, 256, 0, stream>>>(d_in[3], bq, flag, 3072);
  convert_to_f32<<<4, 256, 0, stream>>>(d_in[5], bp, flag, 1024);
  mask_bias<<<(B_ * S_) / 256, 256, 0, stream>>>((const int*)d_in[1], mbias, B_ * S_);
  transpose_conv<<<dim3(96, 32), 256, 0, stream>>>(d_in[2], WqkvTu, flag, 1024, 3072);
  transpose_conv<<<dim3(32, 32), 256, 0, stream>>>(d_in[4], WprojTu, flag, 1024, 1024);

  const int nchunk = merged ? 1 : B_;
  const int bsz = merged ? B_ : 1;
  const int Mc = bsz * S_;
  for (int c = 0; c < nchunk; ++c) {
    long long off = (long long)c * S_ * E_;
    gemm_x_w<<<dim3(Mc / 128, 3072 / 128), 256, 0, stream>>>(
        d_in[0], off, (const __hip_bfloat16*)WqkvTu, bq, flag, qkv, Mc, 3072, 1024);
    attn_flash<<<dim3(S_ / 128, bsz * H_), 512, 0, stream>>>(
        qkv, mbias + (size_t)c * S_, attno);
    gemm_p_out<<<dim3(Mc / 128, 1024 / 128), 256, 0, stream>>>(
        attno, (const __hip_bfloat16*)WprojTu, bp, flag, d_out, off, Mc, 1024, 1024);
  }
}